// Round 1
// baseline (7902.740 us; speedup 1.0000x reference)
//
#include <hip/hip_runtime.h>
#include <hip/hip_fp16.h>

namespace {

constexpr int NB = 16;
constexpr int MM = 2048;
constexpr int NN = 2048;
constexpr float NEG_INV_EPS = -10.0f;   // -1/epsilon, epsilon = 0.1
constexpr int ITERS = 100;

// ---- K-source abstraction: fp16 staged kernel matrix, or recompute from C ----

struct KHalf {
  const __half* p;
  __device__ __forceinline__ void load8(size_t i, float* o) const {
    uint4 v = *reinterpret_cast<const uint4*>(p + i);
    const __half2* h = reinterpret_cast<const __half2*>(&v);
    float2 f0 = __half22float2(h[0]);
    float2 f1 = __half22float2(h[1]);
    float2 f2 = __half22float2(h[2]);
    float2 f3 = __half22float2(h[3]);
    o[0] = f0.x; o[1] = f0.y; o[2] = f1.x; o[3] = f1.y;
    o[4] = f2.x; o[5] = f2.y; o[6] = f3.x; o[7] = f3.y;
  }
};

struct KFromC {
  const float* p;
  __device__ __forceinline__ void load8(size_t i, float* o) const {
    float4 c0 = *reinterpret_cast<const float4*>(p + i);
    float4 c1 = *reinterpret_cast<const float4*>(p + i + 4);
    o[0] = __expf(NEG_INV_EPS * c0.x); o[1] = __expf(NEG_INV_EPS * c0.y);
    o[2] = __expf(NEG_INV_EPS * c0.z); o[3] = __expf(NEG_INV_EPS * c0.w);
    o[4] = __expf(NEG_INV_EPS * c1.x); o[5] = __expf(NEG_INV_EPS * c1.y);
    o[6] = __expf(NEG_INV_EPS * c1.z); o[7] = __expf(NEG_INV_EPS * c1.w);
  }
};

// ---- Stage K = exp(-C/eps) as fp16 ----

__global__ void __launch_bounds__(256) build_k(const float* __restrict__ C,
                                               __half* __restrict__ K) {
  const size_t stride = (size_t)gridDim.x * blockDim.x * 8;
  const size_t total = (size_t)NB * MM * NN;
  for (size_t i = ((size_t)blockIdx.x * blockDim.x + threadIdx.x) * 8;
       i < total; i += stride) {
    float4 c0 = *reinterpret_cast<const float4*>(C + i);
    float4 c1 = *reinterpret_cast<const float4*>(C + i + 4);
    __half2 h[4];
    h[0] = __floats2half2_rn(__expf(NEG_INV_EPS * c0.x), __expf(NEG_INV_EPS * c0.y));
    h[1] = __floats2half2_rn(__expf(NEG_INV_EPS * c0.z), __expf(NEG_INV_EPS * c0.w));
    h[2] = __floats2half2_rn(__expf(NEG_INV_EPS * c1.x), __expf(NEG_INV_EPS * c1.y));
    h[3] = __floats2half2_rn(__expf(NEG_INV_EPS * c1.z), __expf(NEG_INV_EPS * c1.w));
    *reinterpret_cast<uint4*>(K + i) = *reinterpret_cast<uint4*>(h);
  }
}

// ---- Fused Sinkhorn iteration, single pass over K ----
// grid = NB*32 blocks (one 64-row chunk each), 512 threads (8 waves).
// Each wave owns 8 consecutive rows. Per row: load the wave's 2048-wide row
// fragment into registers ONCE, dot with w (in registers), butterfly-reduce
// (all lanes end with the full sum), compute z redundantly per lane, and
// immediately accumulate column partials from the SAME registers. K is read
// exactly once from HBM per iteration; no LDS/HBM re-read, no barrier in the
// main loop. Cross-wave column reduction via rotated LDS atomicAdd (2-way
// bank aliasing = free), then one global atomic sweep per block.

template <class KS>
__global__ void __launch_bounds__(512, 2) sink_iter(KS ks,
    const float* __restrict__ a, const float* __restrict__ bm,
    const float* __restrict__ s_cur, float* __restrict__ s_acc,
    float* __restrict__ s_zero, float* __restrict__ z_out) {
  __shared__ __align__(16) float wsh[NN];
  const int b = blockIdx.x >> 5;
  const int chunk = blockIdx.x & 31;
  const int tid = threadIdx.x;
  const int bbase = b * NN;

  {  // cooperative w = b * rcp(s) into LDS, vectorized (512 thr x float4)
    const float4 b4 = *reinterpret_cast<const float4*>(bm + bbase + tid * 4);
    const float4 s4 = *reinterpret_cast<const float4*>(s_cur + bbase + tid * 4);
    float4 w4;
    w4.x = b4.x * __builtin_amdgcn_rcpf(s4.x);
    w4.y = b4.y * __builtin_amdgcn_rcpf(s4.y);
    w4.z = b4.z * __builtin_amdgcn_rcpf(s4.z);
    w4.w = b4.w * __builtin_amdgcn_rcpf(s4.w);
    *reinterpret_cast<float4*>(&wsh[tid * 4]) = w4;
  }
  if (tid < 64) s_zero[bbase + chunk * 64 + tid] = 0.0f;
  __syncthreads();

  const int wave = tid >> 6;
  const int lane = tid & 63;

  // per-lane w fragment (32 floats), columns k*512 + lane*8 + m
  float wreg[32];
#pragma unroll
  for (int k = 0; k < 4; ++k) {
    const float4* w4 = reinterpret_cast<const float4*>(&wsh[k * 512 + lane * 8]);
    const float4 wa = w4[0], wb = w4[1];
    wreg[k * 8 + 0] = wa.x; wreg[k * 8 + 1] = wa.y;
    wreg[k * 8 + 2] = wa.z; wreg[k * 8 + 3] = wa.w;
    wreg[k * 8 + 4] = wb.x; wreg[k * 8 + 5] = wb.y;
    wreg[k * 8 + 6] = wb.z; wreg[k * 8 + 7] = wb.w;
  }
  __syncthreads();  // everyone has wreg; wsh is now free

  // repurpose wsh as the block's column accumulator
  *reinterpret_cast<float4*>(&wsh[tid * 4]) = make_float4(0.f, 0.f, 0.f, 0.f);

  const int r0 = chunk * 64 + wave * 8;
  const size_t abase = (size_t)b * MM;
  float colacc[32];
#pragma unroll
  for (int j = 0; j < 32; ++j) colacc[j] = 0.f;

#pragma unroll 2
  for (int rr = 0; rr < 8; ++rr) {
    const int row = r0 + rr;
    const size_t kb = ((size_t)(b * MM + row)) * NN;
    float kvf[32];
#pragma unroll
    for (int k = 0; k < 4; ++k) ks.load8(kb + k * 512 + lane * 8, &kvf[k * 8]);
    float acc0 = 0.f, acc1 = 0.f;
#pragma unroll
    for (int j = 0; j < 16; ++j) {
      acc0 += kvf[2 * j] * wreg[2 * j];
      acc1 += kvf[2 * j + 1] * wreg[2 * j + 1];
    }
    float acc = acc0 + acc1;
#pragma unroll
    for (int off = 32; off; off >>= 1) acc += __shfl_xor(acc, off, 64);
    // every lane holds the full row sum -> compute z redundantly, no broadcast
    const float zv = a[abase + row] * __builtin_amdgcn_rcpf(acc);
    if (lane == 0) z_out[abase + row] = zv;
#pragma unroll
    for (int j = 0; j < 32; ++j) colacc[j] += kvf[j] * zv;
  }

  __syncthreads();  // wsh zeros visible to all waves

  // cross-wave column reduction: rotated order -> each ds_add instruction is
  // exactly 2-way bank-aliased (free on CDNA4)
  const int rot = (lane >> 2) & 7;
#pragma unroll
  for (int mm = 0; mm < 8; ++mm) {
    const int m = (mm + rot) & 7;
#pragma unroll
    for (int k = 0; k < 4; ++k)
      atomicAdd(&wsh[k * 512 + lane * 8 + m], colacc[k * 8 + m]);
  }
  __syncthreads();

  {  // one global atomic sweep per block
    const float4 cs = *reinterpret_cast<const float4*>(&wsh[tid * 4]);
    float* s = s_acc + bbase + tid * 4;
    atomicAdd(&s[0], cs.x);
    atomicAdd(&s[1], cs.y);
    atomicAdd(&s[2], cs.z);
    atomicAdd(&s[3], cs.w);
  }
}

// ---- Final: P = z_i * exp(-C/eps) * w_j (exact C), dist = sum(P*C). ----
// grid = NB*128 blocks (16 rows each), 256 threads, 8 cols per thread.

__global__ void __launch_bounds__(256) final_pass(const float* __restrict__ C,
    const float* __restrict__ z, const float* __restrict__ bm,
    const float* __restrict__ s_fin, float* __restrict__ out) {
  __shared__ __align__(16) float wsh[NN];
  __shared__ float zsh[16];
  __shared__ float red[256];
  const int b = blockIdx.x >> 7;        // / 128
  const int rc = blockIdx.x & 127;
  const int tid = threadIdx.x;
  const int bbase = b * NN;

  for (int j = tid; j < NN; j += 256)
    wsh[j] = bm[bbase + j] * __builtin_amdgcn_rcpf(s_fin[bbase + j]);
  if (tid < 16) zsh[tid] = z[b * MM + rc * 16 + tid];
  __syncthreads();

  float* __restrict__ P = out + NB;
  const int col = tid * 8;
  const float4* w4 = reinterpret_cast<const float4*>(&wsh[col]);
  const float4 wa = w4[0], wb = w4[1];

  float accd = 0.0f;
#pragma unroll 4
  for (int rr = 0; rr < 16; ++rr) {
    const int row = rc * 16 + rr;
    const float zi = zsh[rr];
    const size_t base = ((size_t)(b * MM + row)) * NN + col;
    float4 c0 = *reinterpret_cast<const float4*>(C + base);
    float4 c1 = *reinterpret_cast<const float4*>(C + base + 4);
    float4 p0, p1;
    p0.x = zi * __expf(NEG_INV_EPS * c0.x) * wa.x;
    p0.y = zi * __expf(NEG_INV_EPS * c0.y) * wa.y;
    p0.z = zi * __expf(NEG_INV_EPS * c0.z) * wa.z;
    p0.w = zi * __expf(NEG_INV_EPS * c0.w) * wa.w;
    p1.x = zi * __expf(NEG_INV_EPS * c1.x) * wb.x;
    p1.y = zi * __expf(NEG_INV_EPS * c1.y) * wb.y;
    p1.z = zi * __expf(NEG_INV_EPS * c1.z) * wb.z;
    p1.w = zi * __expf(NEG_INV_EPS * c1.w) * wb.w;
    *reinterpret_cast<float4*>(P + base) = p0;
    *reinterpret_cast<float4*>(P + base + 4) = p1;
    accd += p0.x * c0.x + p0.y * c0.y + p0.z * c0.z + p0.w * c0.w +
            p1.x * c1.x + p1.y * c1.y + p1.z * c1.z + p1.w * c1.w;
  }

  red[tid] = accd;
  __syncthreads();
  if (tid < 128) red[tid] += red[tid + 128];
  __syncthreads();
  if (tid < 64) {
    float v = red[tid] + red[tid + 64];
#pragma unroll
    for (int off = 32; off; off >>= 1) v += __shfl_xor(v, off, 64);
    if (tid == 0) atomicAdd(&out[b], v);
  }
}

}  // namespace

extern "C" void kernel_launch(void* const* d_in, const int* in_sizes, int n_in,
                              void* d_out, int out_size, void* d_ws, size_t ws_size,
                              hipStream_t stream) {
  const float* C  = (const float*)d_in[0];
  const float* a  = (const float*)d_in[1];
  const float* bm = (const float*)d_in[2];
  float* out = (float*)d_out;
  char* ws = (char*)d_ws;

  const size_t VEC = (size_t)NB * MM * sizeof(float);       // 131072 B
  float* z = (float*)(ws);
  float* s[3] = {(float*)(ws + VEC), (float*)(ws + 2 * VEC), (float*)(ws + 3 * VEC)};
  __half* K = (__half*)(ws + 4 * VEC);
  const size_t needK = 4 * VEC + (size_t)NB * MM * NN * sizeof(__half);
  const bool useHalf = (ws_size >= needK);

  hipMemsetAsync(out, 0, NB * sizeof(float), stream);
  // s[0] = b  =>  first iteration sees w = b/s = 1 (i.e. v0 = 0)
  hipMemcpyAsync(s[0], bm, (size_t)NB * NN * sizeof(float),
                 hipMemcpyDeviceToDevice, stream);
  // iter 0 accumulates into s[1]; s[2] is zeroed by iter 0 itself
  hipMemsetAsync(s[1], 0, (size_t)NB * NN * sizeof(float), stream);

  if (useHalf) {
    build_k<<<8192, 256, 0, stream>>>(C, K);
    KHalf ks{K};
    for (int t = 0; t < ITERS; ++t) {
      sink_iter<KHalf><<<NB * 32, 512, 0, stream>>>(
          ks, a, bm, s[t % 3], s[(t + 1) % 3], s[(t + 2) % 3], z);
    }
  } else {
    KFromC ks{C};
    for (int t = 0; t < ITERS; ++t) {
      sink_iter<KFromC><<<NB * 32, 512, 0, stream>>>(
          ks, a, bm, s[t % 3], s[(t + 1) % 3], s[(t + 2) % 3], z);
    }
  }

  final_pass<<<NB * 128, 256, 0, stream>>>(C, z, bm, s[ITERS % 3], out);
}

// Round 2
// 3611.617 us; speedup vs baseline: 2.1881x; 2.1881x over previous
//
#include <hip/hip_runtime.h>
#include <hip/hip_fp16.h>

namespace {

constexpr int NB = 16;
constexpr int MM = 2048;
constexpr int NN = 2048;
constexpr float NEG_INV_EPS = -10.0f;   // -1/epsilon, epsilon = 0.1
constexpr int ITERS = 100;

// ---- K-source abstraction: fp16 staged kernel matrix, or recompute from C.
// load8h: fill 8 floats for the dot AND return the packed fp16 bits for LDS
// staging (phase 2 re-reads them from LDS, never from HBM).

struct KHalf {
  const __half* p;
  __device__ __forceinline__ void load8h(size_t i, float* o, uint4* raw) const {
    uint4 v = *reinterpret_cast<const uint4*>(p + i);
    *raw = v;
    const __half2* h = reinterpret_cast<const __half2*>(&v);
    float2 f0 = __half22float2(h[0]);
    float2 f1 = __half22float2(h[1]);
    float2 f2 = __half22float2(h[2]);
    float2 f3 = __half22float2(h[3]);
    o[0] = f0.x; o[1] = f0.y; o[2] = f1.x; o[3] = f1.y;
    o[4] = f2.x; o[5] = f2.y; o[6] = f3.x; o[7] = f3.y;
  }
};

struct KFromC {
  const float* p;
  __device__ __forceinline__ void load8h(size_t i, float* o, uint4* raw) const {
    float4 c0 = *reinterpret_cast<const float4*>(p + i);
    float4 c1 = *reinterpret_cast<const float4*>(p + i + 4);
    o[0] = __expf(NEG_INV_EPS * c0.x); o[1] = __expf(NEG_INV_EPS * c0.y);
    o[2] = __expf(NEG_INV_EPS * c0.z); o[3] = __expf(NEG_INV_EPS * c0.w);
    o[4] = __expf(NEG_INV_EPS * c1.x); o[5] = __expf(NEG_INV_EPS * c1.y);
    o[6] = __expf(NEG_INV_EPS * c1.z); o[7] = __expf(NEG_INV_EPS * c1.w);
    __half2 h[4];
    h[0] = __floats2half2_rn(o[0], o[1]);
    h[1] = __floats2half2_rn(o[2], o[3]);
    h[2] = __floats2half2_rn(o[4], o[5]);
    h[3] = __floats2half2_rn(o[6], o[7]);
    *raw = *reinterpret_cast<uint4*>(h);
  }
};

// ---- Stage K = exp(-C/eps) as fp16 ----

__global__ void __launch_bounds__(256) build_k(const float* __restrict__ C,
                                               __half* __restrict__ K) {
  const size_t stride = (size_t)gridDim.x * blockDim.x * 8;
  const size_t total = (size_t)NB * MM * NN;
  for (size_t i = ((size_t)blockIdx.x * blockDim.x + threadIdx.x) * 8;
       i < total; i += stride) {
    float4 c0 = *reinterpret_cast<const float4*>(C + i);
    float4 c1 = *reinterpret_cast<const float4*>(C + i + 4);
    __half2 h[4];
    h[0] = __floats2half2_rn(__expf(NEG_INV_EPS * c0.x), __expf(NEG_INV_EPS * c0.y));
    h[1] = __floats2half2_rn(__expf(NEG_INV_EPS * c0.z), __expf(NEG_INV_EPS * c0.w));
    h[2] = __floats2half2_rn(__expf(NEG_INV_EPS * c1.x), __expf(NEG_INV_EPS * c1.y));
    h[3] = __floats2half2_rn(__expf(NEG_INV_EPS * c1.z), __expf(NEG_INV_EPS * c1.w));
    *reinterpret_cast<uint4*>(K + i) = *reinterpret_cast<uint4*>(h);
  }
}

// ---- Fused Sinkhorn iteration ----
// grid = NB*32 blocks (one 64-row chunk each), 512 threads (8 waves).
// Phase 1 (per 16-row sub-chunk): 8 waves x 2 rows, full-row dot with w in
//   registers -> z. The fp16 row bits are ALSO spilled to LDS (ksh) as they
//   stream through registers.
// Phase 2: column partials over the same 16 rows, read from LDS (not HBM).
// K is fetched from HBM exactly ONCE per iteration (~134 MB), vs 2x before
// (phase-2 HBM re-reads were missing L2: live window 64 blocks/XCD x 64 KB
// = 4 MiB = the whole per-XCD L2).

template <class KS>
__global__ void __launch_bounds__(512, 4) sink_iter(KS ks,
    const float* __restrict__ a, const float* __restrict__ bm,
    const float* __restrict__ s_cur, float* __restrict__ s_acc,
    float* __restrict__ s_zero, float* __restrict__ z_out) {
  __shared__ __align__(16) __half ksh[16][NN];   // 64 KB staged sub-chunk
  __shared__ __align__(16) float wsh[NN];        // 8 KB
  __shared__ float zsh[16];
  const int b = blockIdx.x >> 5;
  const int chunk = blockIdx.x & 31;
  const int tid = threadIdx.x;
  const int bbase = b * NN;

  {  // cooperative w = b * rcp(s) into LDS, vectorized (512 thr x float4)
    const float4 b4 = *reinterpret_cast<const float4*>(bm + bbase + tid * 4);
    const float4 s4 = *reinterpret_cast<const float4*>(s_cur + bbase + tid * 4);
    float4 w4;
    w4.x = b4.x * __builtin_amdgcn_rcpf(s4.x);
    w4.y = b4.y * __builtin_amdgcn_rcpf(s4.y);
    w4.z = b4.z * __builtin_amdgcn_rcpf(s4.z);
    w4.w = b4.w * __builtin_amdgcn_rcpf(s4.w);
    *reinterpret_cast<float4*>(&wsh[tid * 4]) = w4;
  }
  if (tid < 64) s_zero[bbase + chunk * 64 + tid] = 0.0f;
  __syncthreads();

  const int wave = tid >> 6;
  const int lane = tid & 63;

  // per-lane w fragment (32 floats), reused for every row this wave processes
  float wreg[32];
#pragma unroll
  for (int k = 0; k < 4; ++k) {
    const float4* w4 = reinterpret_cast<const float4*>(&wsh[k * 512 + lane * 8]);
    const float4 wa = w4[0], wb = w4[1];
    wreg[k * 8 + 0] = wa.x; wreg[k * 8 + 1] = wa.y;
    wreg[k * 8 + 2] = wa.z; wreg[k * 8 + 3] = wa.w;
    wreg[k * 8 + 4] = wb.x; wreg[k * 8 + 5] = wb.y;
    wreg[k * 8 + 6] = wb.z; wreg[k * 8 + 7] = wb.w;
  }

  const int r0 = chunk * 64;
  const int mycol = tid * 4;
  float colacc[4] = {0.f, 0.f, 0.f, 0.f};

  for (int sc = 0; sc < 4; ++sc) {
    const int rowbase = r0 + sc * 16;
    // ---- phase 1: row dots for 16 rows (8 waves x 2 rows), stage to LDS ----
#pragma unroll
    for (int rr = 0; rr < 2; ++rr) {
      const int lrow = wave * 2 + rr;        // 0..15 within sub-chunk
      const int row = rowbase + lrow;
      const size_t kb = ((size_t)(b * MM + row)) * NN;
      float acc = 0.f;
#pragma unroll
      for (int k = 0; k < 4; ++k) {
        float kv[8];
        uint4 raw;
        ks.load8h(kb + k * 512 + lane * 8, kv, &raw);
        *reinterpret_cast<uint4*>(&ksh[lrow][k * 512 + lane * 8]) = raw;
#pragma unroll
        for (int m = 0; m < 8; ++m) acc += kv[m] * wreg[k * 8 + m];
      }
#pragma unroll
      for (int off = 32; off; off >>= 1) acc += __shfl_xor(acc, off, 64);
      if (lane == 0) {
        const float zv = a[b * MM + row] * __builtin_amdgcn_rcpf(acc);
        zsh[lrow] = zv;
        z_out[b * MM + row] = zv;
      }
    }
    __syncthreads();
    // ---- phase 2: column partials over the same 16 rows, from LDS ----
#pragma unroll 4
    for (int r = 0; r < 16; ++r) {
      const float zi = zsh[r];
      uint2 rv = *reinterpret_cast<const uint2*>(&ksh[r][mycol]);
      const __half2* h = reinterpret_cast<const __half2*>(&rv);
      const float2 f01 = __half22float2(h[0]);
      const float2 f23 = __half22float2(h[1]);
      colacc[0] += f01.x * zi;
      colacc[1] += f01.y * zi;
      colacc[2] += f23.x * zi;
      colacc[3] += f23.y * zi;
    }
    __syncthreads();   // phase-2 readers done before next sub-chunk overwrites ksh
  }

  float* s = s_acc + bbase + mycol;
#pragma unroll
  for (int m = 0; m < 4; ++m) atomicAdd(&s[m], colacc[m]);
}

// ---- Final: P = z_i * exp(-C/eps) * w_j (exact C), dist = sum(P*C). ----
// grid = NB*128 blocks (16 rows each), 256 threads, 8 cols per thread.
// Reads C (256 MB) + writes P (256 MB) -> ~81 µs roofline, already there.

__global__ void __launch_bounds__(256) final_pass(const float* __restrict__ C,
    const float* __restrict__ z, const float* __restrict__ bm,
    const float* __restrict__ s_fin, float* __restrict__ out) {
  __shared__ __align__(16) float wsh[NN];
  __shared__ float zsh[16];
  __shared__ float red[256];
  const int b = blockIdx.x >> 7;        // / 128
  const int rc = blockIdx.x & 127;
  const int tid = threadIdx.x;
  const int bbase = b * NN;

  for (int j = tid; j < NN; j += 256)
    wsh[j] = bm[bbase + j] * __builtin_amdgcn_rcpf(s_fin[bbase + j]);
  if (tid < 16) zsh[tid] = z[b * MM + rc * 16 + tid];
  __syncthreads();

  float* __restrict__ P = out + NB;
  const int col = tid * 8;
  const float4* w4 = reinterpret_cast<const float4*>(&wsh[col]);
  const float4 wa = w4[0], wb = w4[1];

  float accd = 0.0f;
#pragma unroll 4
  for (int rr = 0; rr < 16; ++rr) {
    const int row = rc * 16 + rr;
    const float zi = zsh[rr];
    const size_t base = ((size_t)(b * MM + row)) * NN + col;
    float4 c0 = *reinterpret_cast<const float4*>(C + base);
    float4 c1 = *reinterpret_cast<const float4*>(C + base + 4);
    float4 p0, p1;
    p0.x = zi * __expf(NEG_INV_EPS * c0.x) * wa.x;
    p0.y = zi * __expf(NEG_INV_EPS * c0.y) * wa.y;
    p0.z = zi * __expf(NEG_INV_EPS * c0.z) * wa.z;
    p0.w = zi * __expf(NEG_INV_EPS * c0.w) * wa.w;
    p1.x = zi * __expf(NEG_INV_EPS * c1.x) * wb.x;
    p1.y = zi * __expf(NEG_INV_EPS * c1.y) * wb.y;
    p1.z = zi * __expf(NEG_INV_EPS * c1.z) * wb.z;
    p1.w = zi * __expf(NEG_INV_EPS * c1.w) * wb.w;
    *reinterpret_cast<float4*>(P + base) = p0;
    *reinterpret_cast<float4*>(P + base + 4) = p1;
    accd += p0.x * c0.x + p0.y * c0.y + p0.z * c0.z + p0.w * c0.w +
            p1.x * c1.x + p1.y * c1.y + p1.z * c1.z + p1.w * c1.w;
  }

  red[tid] = accd;
  __syncthreads();
  if (tid < 128) red[tid] += red[tid + 128];
  __syncthreads();
  if (tid < 64) {
    float v = red[tid] + red[tid + 64];
#pragma unroll
    for (int off = 32; off; off >>= 1) v += __shfl_xor(v, off, 64);
    if (tid == 0) atomicAdd(&out[b], v);
  }
}

}  // namespace

extern "C" void kernel_launch(void* const* d_in, const int* in_sizes, int n_in,
                              void* d_out, int out_size, void* d_ws, size_t ws_size,
                              hipStream_t stream) {
  const float* C  = (const float*)d_in[0];
  const float* a  = (const float*)d_in[1];
  const float* bm = (const float*)d_in[2];
  float* out = (float*)d_out;
  char* ws = (char*)d_ws;

  const size_t VEC = (size_t)NB * MM * sizeof(float);       // 131072 B
  float* z = (float*)(ws);
  float* s[3] = {(float*)(ws + VEC), (float*)(ws + 2 * VEC), (float*)(ws + 3 * VEC)};
  __half* K = (__half*)(ws + 4 * VEC);
  const size_t needK = 4 * VEC + (size_t)NB * MM * NN * sizeof(__half);
  const bool useHalf = (ws_size >= needK);

  hipMemsetAsync(out, 0, NB * sizeof(float), stream);
  // s[0] = b  =>  first iteration sees w = b/s = 1 (i.e. v0 = 0)
  hipMemcpyAsync(s[0], bm, (size_t)NB * NN * sizeof(float),
                 hipMemcpyDeviceToDevice, stream);
  // iter 0 accumulates into s[1]; s[2] is zeroed by iter 0 itself
  hipMemsetAsync(s[1], 0, (size_t)NB * NN * sizeof(float), stream);

  if (useHalf) {
    build_k<<<8192, 256, 0, stream>>>(C, K);
    KHalf ks{K};
    for (int t = 0; t < ITERS; ++t) {
      sink_iter<KHalf><<<NB * 32, 512, 0, stream>>>(
          ks, a, bm, s[t % 3], s[(t + 1) % 3], s[(t + 2) % 3], z);
    }
  } else {
    KFromC ks{C};
    for (int t = 0; t < ITERS; ++t) {
      sink_iter<KFromC><<<NB * 32, 512, 0, stream>>>(
          ks, a, bm, s[t % 3], s[(t + 1) % 3], s[(t + 2) % 3], z);
    }
  }

  final_pass<<<NB * 128, 256, 0, stream>>>(C, z, bm, s[ITERS % 3], out);
}

// Round 3
// 3594.251 us; speedup vs baseline: 2.1987x; 1.0048x over previous
//
#include <hip/hip_runtime.h>
#include <hip/hip_fp16.h>

namespace {

constexpr int NB = 16;
constexpr int MM = 2048;
constexpr int NN = 2048;
constexpr float NEG_INV_EPS = -10.0f;   // -1/epsilon, epsilon = 0.1
constexpr int ITERS = 100;

// ---- Stage K = exp(-C/eps) as fp16 ----

__global__ void __launch_bounds__(256) build_k(const float* __restrict__ C,
                                               __half* __restrict__ K) {
  const size_t stride = (size_t)gridDim.x * blockDim.x * 8;
  const size_t total = (size_t)NB * MM * NN;
  for (size_t i = ((size_t)blockIdx.x * blockDim.x + threadIdx.x) * 8;
       i < total; i += stride) {
    float4 c0 = *reinterpret_cast<const float4*>(C + i);
    float4 c1 = *reinterpret_cast<const float4*>(C + i + 4);
    __half2 h[4];
    h[0] = __floats2half2_rn(__expf(NEG_INV_EPS * c0.x), __expf(NEG_INV_EPS * c0.y));
    h[1] = __floats2half2_rn(__expf(NEG_INV_EPS * c0.z), __expf(NEG_INV_EPS * c0.w));
    h[2] = __floats2half2_rn(__expf(NEG_INV_EPS * c1.x), __expf(NEG_INV_EPS * c1.y));
    h[3] = __floats2half2_rn(__expf(NEG_INV_EPS * c1.z), __expf(NEG_INV_EPS * c1.w));
    *reinterpret_cast<uint4*>(K + i) = *reinterpret_cast<uint4*>(h);
  }
}

// ---- Pipelined fused Sinkhorn iteration (fp16 K path) ----
// grid = NB*32 blocks (one 64-row chunk each), 512 threads (8 waves).
// 8 sub-chunks of 8 rows (1 row per wave), ksh double-buffered (2 x 32 KB).
// Per sub-chunk region: (1) ISSUE next sub-chunk's global loads (raw fp16 ->
// regs, no wait), (2) phase-2 column accumulation from the CURRENT LDS buffer
// (hides the loads' latency), (3) CONSUME: ds_write raw bits to the next
// buffer + dot + butterfly-reduce -> z, (4) one barrier. HBM load issue
// happens in EVERY inter-barrier region -- no LDS-only phase during which
// the memory system starves (the R2 structure idled HBM ~1/3 of the time).
// K is fetched from HBM exactly once per iteration (~134 MB).

__global__ void __launch_bounds__(512, 4) sink_iter_h(
    const __half* __restrict__ Kp,
    const float* __restrict__ a, const float* __restrict__ bm,
    const float* __restrict__ s_cur, float* __restrict__ s_acc,
    float* __restrict__ s_zero, float* __restrict__ z_out) {
  __shared__ __align__(16) __half ksh[2][8][NN];   // 64 KB, double-buffered
  __shared__ __align__(16) float wsh[NN];          // 8 KB
  __shared__ float zsh[2][8];
  const int b = blockIdx.x >> 5;
  const int chunk = blockIdx.x & 31;
  const int tid = threadIdx.x;
  const int bbase = b * NN;

  {  // cooperative w = b * rcp(s) into LDS, vectorized (512 thr x float4)
    const float4 b4 = *reinterpret_cast<const float4*>(bm + bbase + tid * 4);
    const float4 s4 = *reinterpret_cast<const float4*>(s_cur + bbase + tid * 4);
    float4 w4;
    w4.x = b4.x * __builtin_amdgcn_rcpf(s4.x);
    w4.y = b4.y * __builtin_amdgcn_rcpf(s4.y);
    w4.z = b4.z * __builtin_amdgcn_rcpf(s4.z);
    w4.w = b4.w * __builtin_amdgcn_rcpf(s4.w);
    *reinterpret_cast<float4*>(&wsh[tid * 4]) = w4;
  }
  if (tid < 64) s_zero[bbase + chunk * 64 + tid] = 0.0f;
  __syncthreads();

  const int wave = tid >> 6;
  const int lane = tid & 63;

  // per-lane w fragment (32 floats), reused for every row this wave processes
  float wreg[32];
#pragma unroll
  for (int k = 0; k < 4; ++k) {
    const float4* w4 = reinterpret_cast<const float4*>(&wsh[k * 512 + lane * 8]);
    const float4 wa = w4[0], wb = w4[1];
    wreg[k * 8 + 0] = wa.x; wreg[k * 8 + 1] = wa.y;
    wreg[k * 8 + 2] = wa.z; wreg[k * 8 + 3] = wa.w;
    wreg[k * 8 + 4] = wb.x; wreg[k * 8 + 5] = wb.y;
    wreg[k * 8 + 6] = wb.z; wreg[k * 8 + 7] = wb.w;
  }

  const int r0 = chunk * 64;
  const int mycol = tid * 4;
  const size_t abase = (size_t)b * MM;
  float colacc[4] = {0.f, 0.f, 0.f, 0.f};
  uint4 kr[4];

  // ---- prologue: load + consume sub-chunk 0 into buffer 0 ----
  {
    const int row = r0 + wave;
    const size_t kb = (abase + row) * NN;
    const float av = a[abase + row];
#pragma unroll
    for (int k = 0; k < 4; ++k)
      kr[k] = *reinterpret_cast<const uint4*>(Kp + kb + k * 512 + lane * 8);
    float acc = 0.f;
#pragma unroll
    for (int k = 0; k < 4; ++k) {
      *reinterpret_cast<uint4*>(&ksh[0][wave][k * 512 + lane * 8]) = kr[k];
      const __half2* h = reinterpret_cast<const __half2*>(&kr[k]);
      const float2 f0 = __half22float2(h[0]);
      const float2 f1 = __half22float2(h[1]);
      const float2 f2 = __half22float2(h[2]);
      const float2 f3 = __half22float2(h[3]);
      acc += f0.x * wreg[k * 8 + 0] + f0.y * wreg[k * 8 + 1] +
             f1.x * wreg[k * 8 + 2] + f1.y * wreg[k * 8 + 3] +
             f2.x * wreg[k * 8 + 4] + f2.y * wreg[k * 8 + 5] +
             f3.x * wreg[k * 8 + 6] + f3.y * wreg[k * 8 + 7];
    }
#pragma unroll
    for (int off = 32; off; off >>= 1) acc += __shfl_xor(acc, off, 64);
    const float zv = av * __builtin_amdgcn_rcpf(acc);
    if (lane == 0) {
      zsh[0][wave] = zv;
      z_out[abase + row] = zv;
    }
  }
  __syncthreads();

  // ---- main pipeline: 8 sub-chunks ----
  for (int sc = 0; sc < 8; ++sc) {
    const int cb = sc & 1, nb = cb ^ 1;
    float av = 0.f;
    if (sc < 7) {  // ISSUE next sub-chunk's loads (no wait yet)
      const int row = r0 + (sc + 1) * 8 + wave;
      const size_t kb = (abase + row) * NN;
      av = a[abase + row];
#pragma unroll
      for (int k = 0; k < 4; ++k)
        kr[k] = *reinterpret_cast<const uint4*>(Kp + kb + k * 512 + lane * 8);
    }
    // phase 2 on current buffer (pure LDS) -- runs under the loads' latency
#pragma unroll
    for (int r = 0; r < 8; ++r) {
      const float zi = zsh[cb][r];
      uint2 rv = *reinterpret_cast<const uint2*>(&ksh[cb][r][mycol]);
      const __half2* h = reinterpret_cast<const __half2*>(&rv);
      const float2 f01 = __half22float2(h[0]);
      const float2 f23 = __half22float2(h[1]);
      colacc[0] += f01.x * zi;
      colacc[1] += f01.y * zi;
      colacc[2] += f23.x * zi;
      colacc[3] += f23.y * zi;
    }
    if (sc < 7) {  // CONSUME: stage to next buffer + row dot -> z
      const int row = r0 + (sc + 1) * 8 + wave;
      float acc = 0.f;
#pragma unroll
      for (int k = 0; k < 4; ++k) {
        *reinterpret_cast<uint4*>(&ksh[nb][wave][k * 512 + lane * 8]) = kr[k];
        const __half2* h = reinterpret_cast<const __half2*>(&kr[k]);
        const float2 f0 = __half22float2(h[0]);
        const float2 f1 = __half22float2(h[1]);
        const float2 f2 = __half22float2(h[2]);
        const float2 f3 = __half22float2(h[3]);
        acc += f0.x * wreg[k * 8 + 0] + f0.y * wreg[k * 8 + 1] +
               f1.x * wreg[k * 8 + 2] + f1.y * wreg[k * 8 + 3] +
               f2.x * wreg[k * 8 + 4] + f2.y * wreg[k * 8 + 5] +
               f3.x * wreg[k * 8 + 6] + f3.y * wreg[k * 8 + 7];
      }
#pragma unroll
      for (int off = 32; off; off >>= 1) acc += __shfl_xor(acc, off, 64);
      const float zv = av * __builtin_amdgcn_rcpf(acc);
      if (lane == 0) {
        zsh[nb][wave] = zv;
        z_out[abase + row] = zv;
      }
    }
    __syncthreads();
  }

  float* s = s_acc + bbase + mycol;
#pragma unroll
  for (int m = 0; m < 4; ++m) atomicAdd(&s[m], colacc[m]);
}

// ---- Fallback (no workspace for fp16 K): R2 two-phase kernel, recompute
// K from C on the fly. Correctness path only.

struct KFromC {
  const float* p;
  __device__ __forceinline__ void load8h(size_t i, float* o, uint4* raw) const {
    float4 c0 = *reinterpret_cast<const float4*>(p + i);
    float4 c1 = *reinterpret_cast<const float4*>(p + i + 4);
    o[0] = __expf(NEG_INV_EPS * c0.x); o[1] = __expf(NEG_INV_EPS * c0.y);
    o[2] = __expf(NEG_INV_EPS * c0.z); o[3] = __expf(NEG_INV_EPS * c0.w);
    o[4] = __expf(NEG_INV_EPS * c1.x); o[5] = __expf(NEG_INV_EPS * c1.y);
    o[6] = __expf(NEG_INV_EPS * c1.z); o[7] = __expf(NEG_INV_EPS * c1.w);
    __half2 h[4];
    h[0] = __floats2half2_rn(o[0], o[1]);
    h[1] = __floats2half2_rn(o[2], o[3]);
    h[2] = __floats2half2_rn(o[4], o[5]);
    h[3] = __floats2half2_rn(o[6], o[7]);
    *raw = *reinterpret_cast<uint4*>(h);
  }
};

template <class KS>
__global__ void __launch_bounds__(512, 4) sink_iter(KS ks,
    const float* __restrict__ a, const float* __restrict__ bm,
    const float* __restrict__ s_cur, float* __restrict__ s_acc,
    float* __restrict__ s_zero, float* __restrict__ z_out) {
  __shared__ __align__(16) __half ksh[16][NN];   // 64 KB staged sub-chunk
  __shared__ __align__(16) float wsh[NN];        // 8 KB
  __shared__ float zsh[16];
  const int b = blockIdx.x >> 5;
  const int chunk = blockIdx.x & 31;
  const int tid = threadIdx.x;
  const int bbase = b * NN;

  {
    const float4 b4 = *reinterpret_cast<const float4*>(bm + bbase + tid * 4);
    const float4 s4 = *reinterpret_cast<const float4*>(s_cur + bbase + tid * 4);
    float4 w4;
    w4.x = b4.x * __builtin_amdgcn_rcpf(s4.x);
    w4.y = b4.y * __builtin_amdgcn_rcpf(s4.y);
    w4.z = b4.z * __builtin_amdgcn_rcpf(s4.z);
    w4.w = b4.w * __builtin_amdgcn_rcpf(s4.w);
    *reinterpret_cast<float4*>(&wsh[tid * 4]) = w4;
  }
  if (tid < 64) s_zero[bbase + chunk * 64 + tid] = 0.0f;
  __syncthreads();

  const int wave = tid >> 6;
  const int lane = tid & 63;

  float wreg[32];
#pragma unroll
  for (int k = 0; k < 4; ++k) {
    const float4* w4 = reinterpret_cast<const float4*>(&wsh[k * 512 + lane * 8]);
    const float4 wa = w4[0], wb = w4[1];
    wreg[k * 8 + 0] = wa.x; wreg[k * 8 + 1] = wa.y;
    wreg[k * 8 + 2] = wa.z; wreg[k * 8 + 3] = wa.w;
    wreg[k * 8 + 4] = wb.x; wreg[k * 8 + 5] = wb.y;
    wreg[k * 8 + 6] = wb.z; wreg[k * 8 + 7] = wb.w;
  }

  const int r0 = chunk * 64;
  const int mycol = tid * 4;
  float colacc[4] = {0.f, 0.f, 0.f, 0.f};

  for (int sc = 0; sc < 4; ++sc) {
    const int rowbase = r0 + sc * 16;
#pragma unroll
    for (int rr = 0; rr < 2; ++rr) {
      const int lrow = wave * 2 + rr;
      const int row = rowbase + lrow;
      const size_t kb = ((size_t)(b * MM + row)) * NN;
      float acc = 0.f;
#pragma unroll
      for (int k = 0; k < 4; ++k) {
        float kv[8];
        uint4 raw;
        ks.load8h(kb + k * 512 + lane * 8, kv, &raw);
        *reinterpret_cast<uint4*>(&ksh[lrow][k * 512 + lane * 8]) = raw;
#pragma unroll
        for (int m = 0; m < 8; ++m) acc += kv[m] * wreg[k * 8 + m];
      }
#pragma unroll
      for (int off = 32; off; off >>= 1) acc += __shfl_xor(acc, off, 64);
      if (lane == 0) {
        const float zv = a[b * MM + row] * __builtin_amdgcn_rcpf(acc);
        zsh[lrow] = zv;
        z_out[b * MM + row] = zv;
      }
    }
    __syncthreads();
#pragma unroll 4
    for (int r = 0; r < 16; ++r) {
      const float zi = zsh[r];
      uint2 rv = *reinterpret_cast<const uint2*>(&ksh[r][mycol]);
      const __half2* h = reinterpret_cast<const __half2*>(&rv);
      const float2 f01 = __half22float2(h[0]);
      const float2 f23 = __half22float2(h[1]);
      colacc[0] += f01.x * zi;
      colacc[1] += f01.y * zi;
      colacc[2] += f23.x * zi;
      colacc[3] += f23.y * zi;
    }
    __syncthreads();
  }

  float* s = s_acc + bbase + mycol;
#pragma unroll
  for (int m = 0; m < 4; ++m) atomicAdd(&s[m], colacc[m]);
}

// ---- Final: P = z_i * exp(-C/eps) * w_j (exact C), dist = sum(P*C). ----
// grid = NB*128 blocks (16 rows each), 256 threads, 8 cols per thread.

__global__ void __launch_bounds__(256) final_pass(const float* __restrict__ C,
    const float* __restrict__ z, const float* __restrict__ bm,
    const float* __restrict__ s_fin, float* __restrict__ out) {
  __shared__ __align__(16) float wsh[NN];
  __shared__ float zsh[16];
  __shared__ float red[256];
  const int b = blockIdx.x >> 7;        // / 128
  const int rc = blockIdx.x & 127;
  const int tid = threadIdx.x;
  const int bbase = b * NN;

  for (int j = tid; j < NN; j += 256)
    wsh[j] = bm[bbase + j] * __builtin_amdgcn_rcpf(s_fin[bbase + j]);
  if (tid < 16) zsh[tid] = z[b * MM + rc * 16 + tid];
  __syncthreads();

  float* __restrict__ P = out + NB;
  const int col = tid * 8;
  const float4* w4 = reinterpret_cast<const float4*>(&wsh[col]);
  const float4 wa = w4[0], wb = w4[1];

  float accd = 0.0f;
#pragma unroll 4
  for (int rr = 0; rr < 16; ++rr) {
    const int row = rc * 16 + rr;
    const float zi = zsh[rr];
    const size_t base = ((size_t)(b * MM + row)) * NN + col;
    float4 c0 = *reinterpret_cast<const float4*>(C + base);
    float4 c1 = *reinterpret_cast<const float4*>(C + base + 4);
    float4 p0, p1;
    p0.x = zi * __expf(NEG_INV_EPS * c0.x) * wa.x;
    p0.y = zi * __expf(NEG_INV_EPS * c0.y) * wa.y;
    p0.z = zi * __expf(NEG_INV_EPS * c0.z) * wa.z;
    p0.w = zi * __expf(NEG_INV_EPS * c0.w) * wa.w;
    p1.x = zi * __expf(NEG_INV_EPS * c1.x) * wb.x;
    p1.y = zi * __expf(NEG_INV_EPS * c1.y) * wb.y;
    p1.z = zi * __expf(NEG_INV_EPS * c1.z) * wb.z;
    p1.w = zi * __expf(NEG_INV_EPS * c1.w) * wb.w;
    *reinterpret_cast<float4*>(P + base) = p0;
    *reinterpret_cast<float4*>(P + base + 4) = p1;
    accd += p0.x * c0.x + p0.y * c0.y + p0.z * c0.z + p0.w * c0.w +
            p1.x * c1.x + p1.y * c1.y + p1.z * c1.z + p1.w * c1.w;
  }

  red[tid] = accd;
  __syncthreads();
  if (tid < 128) red[tid] += red[tid + 128];
  __syncthreads();
  if (tid < 64) {
    float v = red[tid] + red[tid + 64];
#pragma unroll
    for (int off = 32; off; off >>= 1) v += __shfl_xor(v, off, 64);
    if (tid == 0) atomicAdd(&out[b], v);
  }
}

}  // namespace

extern "C" void kernel_launch(void* const* d_in, const int* in_sizes, int n_in,
                              void* d_out, int out_size, void* d_ws, size_t ws_size,
                              hipStream_t stream) {
  const float* C  = (const float*)d_in[0];
  const float* a  = (const float*)d_in[1];
  const float* bm = (const float*)d_in[2];
  float* out = (float*)d_out;
  char* ws = (char*)d_ws;

  const size_t VEC = (size_t)NB * MM * sizeof(float);       // 131072 B
  float* z = (float*)(ws);
  float* s[3] = {(float*)(ws + VEC), (float*)(ws + 2 * VEC), (float*)(ws + 3 * VEC)};
  __half* K = (__half*)(ws + 4 * VEC);
  const size_t needK = 4 * VEC + (size_t)NB * MM * NN * sizeof(__half);
  const bool useHalf = (ws_size >= needK);

  hipMemsetAsync(out, 0, NB * sizeof(float), stream);
  // s[0] = b  =>  first iteration sees w = b/s = 1 (i.e. v0 = 0)
  hipMemcpyAsync(s[0], bm, (size_t)NB * NN * sizeof(float),
                 hipMemcpyDeviceToDevice, stream);
  // iter 0 accumulates into s[1]; s[2] is zeroed by iter 0 itself
  hipMemsetAsync(s[1], 0, (size_t)NB * NN * sizeof(float), stream);

  if (useHalf) {
    build_k<<<8192, 256, 0, stream>>>(C, K);
    for (int t = 0; t < ITERS; ++t) {
      sink_iter_h<<<NB * 32, 512, 0, stream>>>(
          K, a, bm, s[t % 3], s[(t + 1) % 3], s[(t + 2) % 3], z);
    }
  } else {
    KFromC ks{C};
    for (int t = 0; t < ITERS; ++t) {
      sink_iter<KFromC><<<NB * 32, 512, 0, stream>>>(
          ks, a, bm, s[t % 3], s[(t + 1) % 3], s[(t + 2) % 3], z);
    }
  }

  final_pass<<<NB * 128, 256, 0, stream>>>(C, z, bm, s[ITERS % 3], out);
}

// Round 4
// 3545.529 us; speedup vs baseline: 2.2289x; 1.0137x over previous
//
#include <hip/hip_runtime.h>
#include <hip/hip_fp16.h>
#include <hip/hip_cooperative_groups.h>

namespace cg = cooperative_groups;

namespace {

constexpr int NB = 16;
constexpr int MM = 2048;
constexpr int NN = 2048;
constexpr float NEG_INV_EPS = -10.0f;   // -1/epsilon, epsilon = 0.1
constexpr int ITERS = 100;

// ---- Stage K = exp(-C/eps) as fp16 ----

__global__ void __launch_bounds__(256) build_k(const float* __restrict__ C,
                                               __half* __restrict__ K) {
  const size_t stride = (size_t)gridDim.x * blockDim.x * 8;
  const size_t total = (size_t)NB * MM * NN;
  for (size_t i = ((size_t)blockIdx.x * blockDim.x + threadIdx.x) * 8;
       i < total; i += stride) {
    float4 c0 = *reinterpret_cast<const float4*>(C + i);
    float4 c1 = *reinterpret_cast<const float4*>(C + i + 4);
    __half2 h[4];
    h[0] = __floats2half2_rn(__expf(NEG_INV_EPS * c0.x), __expf(NEG_INV_EPS * c0.y));
    h[1] = __floats2half2_rn(__expf(NEG_INV_EPS * c0.z), __expf(NEG_INV_EPS * c0.w));
    h[2] = __floats2half2_rn(__expf(NEG_INV_EPS * c1.x), __expf(NEG_INV_EPS * c1.y));
    h[3] = __floats2half2_rn(__expf(NEG_INV_EPS * c1.z), __expf(NEG_INV_EPS * c1.w));
    *reinterpret_cast<uint4*>(K + i) = *reinterpret_cast<uint4*>(h);
  }
}

// ---- Fully fused Sinkhorn: all 100 iterations in ONE cooperative kernel ----
// grid = 512 blocks (2/CU co-resident) x 512 threads. Per iteration: stream
// the block's 64-row K chunk once (R3 pipelined core), write 2048 column
// partials NON-atomically to partial[b][chunk][*], grid.sync(), wave 0 of
// each block tree-reduces its own 64-col slice over the 32 chunks and writes
// w = b*rcp(s), grid.sync(). Eliminates: 100 kernel launches, 100 x 1M
// contended global atomics, per-iter s-rotation, z stores (except last iter).

__global__ void __launch_bounds__(512, 4) sink_coop(
    const __half* __restrict__ Kp,
    const float* __restrict__ a, const float* __restrict__ bm,
    float* __restrict__ z_out, float* __restrict__ wbuf,
    float* __restrict__ partial) {
  cg::grid_group grid = cg::this_grid();
  __shared__ __align__(16) __half ksh[2][8][NN];   // 64 KB, double-buffered
  __shared__ __align__(16) float wsh[NN];          // 8 KB
  __shared__ float zsh[2][8];
  const int b = blockIdx.x >> 5;
  const int chunk = blockIdx.x & 31;
  const int tid = threadIdx.x;
  const int bbase = b * NN;
  const int wave = tid >> 6;
  const int lane = tid & 63;
  const int r0 = chunk * 64;
  const int mycol = tid * 4;
  const size_t abase = (size_t)b * MM;

  for (int t = 0; t < ITERS; ++t) {
    // ---- wsh = current w (t=0: w = b/s with s=b => exactly 1.0) ----
    if (t == 0) {
      *reinterpret_cast<float4*>(&wsh[tid * 4]) = make_float4(1.f, 1.f, 1.f, 1.f);
    } else {
      *reinterpret_cast<float4*>(&wsh[tid * 4]) =
          *reinterpret_cast<const float4*>(wbuf + bbase + tid * 4);
    }
    __syncthreads();

    float wreg[32];
#pragma unroll
    for (int k = 0; k < 4; ++k) {
      const float4* w4 = reinterpret_cast<const float4*>(&wsh[k * 512 + lane * 8]);
      const float4 wa = w4[0], wb = w4[1];
      wreg[k * 8 + 0] = wa.x; wreg[k * 8 + 1] = wa.y;
      wreg[k * 8 + 2] = wa.z; wreg[k * 8 + 3] = wa.w;
      wreg[k * 8 + 4] = wb.x; wreg[k * 8 + 5] = wb.y;
      wreg[k * 8 + 6] = wb.z; wreg[k * 8 + 7] = wb.w;
    }

    const bool lastit = (t == ITERS - 1);
    float colacc[4] = {0.f, 0.f, 0.f, 0.f};
    uint4 kr[4];

    // ---- prologue: load + consume sub-chunk 0 into buffer 0 ----
    {
      const int row = r0 + wave;
      const size_t kb = (abase + row) * NN;
      const float av = a[abase + row];
#pragma unroll
      for (int k = 0; k < 4; ++k)
        kr[k] = *reinterpret_cast<const uint4*>(Kp + kb + k * 512 + lane * 8);
      float acc = 0.f;
#pragma unroll
      for (int k = 0; k < 4; ++k) {
        *reinterpret_cast<uint4*>(&ksh[0][wave][k * 512 + lane * 8]) = kr[k];
        const __half2* h = reinterpret_cast<const __half2*>(&kr[k]);
        const float2 f0 = __half22float2(h[0]);
        const float2 f1 = __half22float2(h[1]);
        const float2 f2 = __half22float2(h[2]);
        const float2 f3 = __half22float2(h[3]);
        acc += f0.x * wreg[k * 8 + 0] + f0.y * wreg[k * 8 + 1] +
               f1.x * wreg[k * 8 + 2] + f1.y * wreg[k * 8 + 3] +
               f2.x * wreg[k * 8 + 4] + f2.y * wreg[k * 8 + 5] +
               f3.x * wreg[k * 8 + 6] + f3.y * wreg[k * 8 + 7];
      }
#pragma unroll
      for (int off = 32; off; off >>= 1) acc += __shfl_xor(acc, off, 64);
      const float zv = av * __builtin_amdgcn_rcpf(acc);
      if (lane == 0) {
        zsh[0][wave] = zv;
        if (lastit) z_out[abase + row] = zv;
      }
    }
    __syncthreads();

    // ---- main pipeline: 8 sub-chunks ----
    for (int sc = 0; sc < 8; ++sc) {
      const int cb = sc & 1, nb2 = cb ^ 1;
      float av = 0.f;
      if (sc < 7) {  // ISSUE next sub-chunk's loads (no wait yet)
        const int row = r0 + (sc + 1) * 8 + wave;
        const size_t kb = (abase + row) * NN;
        av = a[abase + row];
#pragma unroll
        for (int k = 0; k < 4; ++k)
          kr[k] = *reinterpret_cast<const uint4*>(Kp + kb + k * 512 + lane * 8);
      }
      // column partials on current buffer (pure LDS)
#pragma unroll
      for (int r = 0; r < 8; ++r) {
        const float zi = zsh[cb][r];
        uint2 rv = *reinterpret_cast<const uint2*>(&ksh[cb][r][mycol]);
        const __half2* h = reinterpret_cast<const __half2*>(&rv);
        const float2 f01 = __half22float2(h[0]);
        const float2 f23 = __half22float2(h[1]);
        colacc[0] += f01.x * zi;
        colacc[1] += f01.y * zi;
        colacc[2] += f23.x * zi;
        colacc[3] += f23.y * zi;
      }
      if (sc < 7) {  // CONSUME: stage to next buffer + row dot -> z
        const int row = r0 + (sc + 1) * 8 + wave;
        float acc = 0.f;
#pragma unroll
        for (int k = 0; k < 4; ++k) {
          *reinterpret_cast<uint4*>(&ksh[nb2][wave][k * 512 + lane * 8]) = kr[k];
          const __half2* h = reinterpret_cast<const __half2*>(&kr[k]);
          const float2 f0 = __half22float2(h[0]);
          const float2 f1 = __half22float2(h[1]);
          const float2 f2 = __half22float2(h[2]);
          const float2 f3 = __half22float2(h[3]);
          acc += f0.x * wreg[k * 8 + 0] + f0.y * wreg[k * 8 + 1] +
                 f1.x * wreg[k * 8 + 2] + f1.y * wreg[k * 8 + 3] +
                 f2.x * wreg[k * 8 + 4] + f2.y * wreg[k * 8 + 5] +
                 f3.x * wreg[k * 8 + 6] + f3.y * wreg[k * 8 + 7];
        }
#pragma unroll
        for (int off = 32; off; off >>= 1) acc += __shfl_xor(acc, off, 64);
        const float zv = av * __builtin_amdgcn_rcpf(acc);
        if (lane == 0) {
          zsh[nb2][wave] = zv;
          if (lastit) z_out[abase + row] = zv;
        }
      }
      __syncthreads();
    }

    // ---- non-atomic partial store: partial[b][chunk][2048] ----
    *reinterpret_cast<float4*>(partial + ((size_t)(b * 32 + chunk)) * NN + mycol) =
        make_float4(colacc[0], colacc[1], colacc[2], colacc[3]);
    __threadfence();
    grid.sync();

    // ---- distributed column reduce: this block owns 64 cols of batch b ----
    if (tid < 64) {
      const int col = chunk * 64 + tid;
      const float* pp = partial + (size_t)b * 32 * NN + col;
      float s0 = 0.f, s1 = 0.f, s2 = 0.f, s3 = 0.f;
#pragma unroll
      for (int c = 0; c < 32; c += 4) {
        s0 += pp[(size_t)(c + 0) * NN];
        s1 += pp[(size_t)(c + 1) * NN];
        s2 += pp[(size_t)(c + 2) * NN];
        s3 += pp[(size_t)(c + 3) * NN];
      }
      const float sv = (s0 + s1) + (s2 + s3);
      wbuf[bbase + col] = bm[bbase + col] * __builtin_amdgcn_rcpf(sv);
    }
    __threadfence();
    grid.sync();
  }
}

// ---- Legacy per-iteration kernel (fallback when coop launch unavailable) ----

__global__ void __launch_bounds__(512, 4) sink_iter_h(
    const __half* __restrict__ Kp,
    const float* __restrict__ a, const float* __restrict__ bm,
    const float* __restrict__ s_cur, float* __restrict__ s_acc,
    float* __restrict__ s_zero, float* __restrict__ z_out) {
  __shared__ __align__(16) __half ksh[2][8][NN];
  __shared__ __align__(16) float wsh[NN];
  __shared__ float zsh[2][8];
  const int b = blockIdx.x >> 5;
  const int chunk = blockIdx.x & 31;
  const int tid = threadIdx.x;
  const int bbase = b * NN;

  {
    const float4 b4 = *reinterpret_cast<const float4*>(bm + bbase + tid * 4);
    const float4 s4 = *reinterpret_cast<const float4*>(s_cur + bbase + tid * 4);
    float4 w4;
    w4.x = b4.x * __builtin_amdgcn_rcpf(s4.x);
    w4.y = b4.y * __builtin_amdgcn_rcpf(s4.y);
    w4.z = b4.z * __builtin_amdgcn_rcpf(s4.z);
    w4.w = b4.w * __builtin_amdgcn_rcpf(s4.w);
    *reinterpret_cast<float4*>(&wsh[tid * 4]) = w4;
  }
  if (tid < 64) s_zero[bbase + chunk * 64 + tid] = 0.0f;
  __syncthreads();

  const int wave = tid >> 6;
  const int lane = tid & 63;

  float wreg[32];
#pragma unroll
  for (int k = 0; k < 4; ++k) {
    const float4* w4 = reinterpret_cast<const float4*>(&wsh[k * 512 + lane * 8]);
    const float4 wa = w4[0], wb = w4[1];
    wreg[k * 8 + 0] = wa.x; wreg[k * 8 + 1] = wa.y;
    wreg[k * 8 + 2] = wa.z; wreg[k * 8 + 3] = wa.w;
    wreg[k * 8 + 4] = wb.x; wreg[k * 8 + 5] = wb.y;
    wreg[k * 8 + 6] = wb.z; wreg[k * 8 + 7] = wb.w;
  }

  const int r0 = chunk * 64;
  const int mycol = tid * 4;
  const size_t abase = (size_t)b * MM;
  float colacc[4] = {0.f, 0.f, 0.f, 0.f};
  uint4 kr[4];

  {
    const int row = r0 + wave;
    const size_t kb = (abase + row) * NN;
    const float av = a[abase + row];
#pragma unroll
    for (int k = 0; k < 4; ++k)
      kr[k] = *reinterpret_cast<const uint4*>(Kp + kb + k * 512 + lane * 8);
    float acc = 0.f;
#pragma unroll
    for (int k = 0; k < 4; ++k) {
      *reinterpret_cast<uint4*>(&ksh[0][wave][k * 512 + lane * 8]) = kr[k];
      const __half2* h = reinterpret_cast<const __half2*>(&kr[k]);
      const float2 f0 = __half22float2(h[0]);
      const float2 f1 = __half22float2(h[1]);
      const float2 f2 = __half22float2(h[2]);
      const float2 f3 = __half22float2(h[3]);
      acc += f0.x * wreg[k * 8 + 0] + f0.y * wreg[k * 8 + 1] +
             f1.x * wreg[k * 8 + 2] + f1.y * wreg[k * 8 + 3] +
             f2.x * wreg[k * 8 + 4] + f2.y * wreg[k * 8 + 5] +
             f3.x * wreg[k * 8 + 6] + f3.y * wreg[k * 8 + 7];
    }
#pragma unroll
    for (int off = 32; off; off >>= 1) acc += __shfl_xor(acc, off, 64);
    const float zv = av * __builtin_amdgcn_rcpf(acc);
    if (lane == 0) {
      zsh[0][wave] = zv;
      z_out[abase + row] = zv;
    }
  }
  __syncthreads();

  for (int sc = 0; sc < 8; ++sc) {
    const int cb = sc & 1, nb2 = cb ^ 1;
    float av = 0.f;
    if (sc < 7) {
      const int row = r0 + (sc + 1) * 8 + wave;
      const size_t kb = (abase + row) * NN;
      av = a[abase + row];
#pragma unroll
      for (int k = 0; k < 4; ++k)
        kr[k] = *reinterpret_cast<const uint4*>(Kp + kb + k * 512 + lane * 8);
    }
#pragma unroll
    for (int r = 0; r < 8; ++r) {
      const float zi = zsh[cb][r];
      uint2 rv = *reinterpret_cast<const uint2*>(&ksh[cb][r][mycol]);
      const __half2* h = reinterpret_cast<const __half2*>(&rv);
      const float2 f01 = __half22float2(h[0]);
      const float2 f23 = __half22float2(h[1]);
      colacc[0] += f01.x * zi;
      colacc[1] += f01.y * zi;
      colacc[2] += f23.x * zi;
      colacc[3] += f23.y * zi;
    }
    if (sc < 7) {
      const int row = r0 + (sc + 1) * 8 + wave;
      float acc = 0.f;
#pragma unroll
      for (int k = 0; k < 4; ++k) {
        *reinterpret_cast<uint4*>(&ksh[nb2][wave][k * 512 + lane * 8]) = kr[k];
        const __half2* h = reinterpret_cast<const __half2*>(&kr[k]);
        const float2 f0 = __half22float2(h[0]);
        const float2 f1 = __half22float2(h[1]);
        const float2 f2 = __half22float2(h[2]);
        const float2 f3 = __half22float2(h[3]);
        acc += f0.x * wreg[k * 8 + 0] + f0.y * wreg[k * 8 + 1] +
               f1.x * wreg[k * 8 + 2] + f1.y * wreg[k * 8 + 3] +
               f2.x * wreg[k * 8 + 4] + f2.y * wreg[k * 8 + 5] +
               f3.x * wreg[k * 8 + 6] + f3.y * wreg[k * 8 + 7];
      }
#pragma unroll
      for (int off = 32; off; off >>= 1) acc += __shfl_xor(acc, off, 64);
      const float zv = av * __builtin_amdgcn_rcpf(acc);
      if (lane == 0) {
        zsh[nb2][wave] = zv;
        z_out[abase + row] = zv;
      }
    }
    __syncthreads();
  }

  float* s = s_acc + bbase + mycol;
#pragma unroll
  for (int m = 0; m < 4; ++m) atomicAdd(&s[m], colacc[m]);
}

// ---- No-workspace fallback: recompute K from C ----

struct KFromC {
  const float* p;
  __device__ __forceinline__ void load8h(size_t i, float* o, uint4* raw) const {
    float4 c0 = *reinterpret_cast<const float4*>(p + i);
    float4 c1 = *reinterpret_cast<const float4*>(p + i + 4);
    o[0] = __expf(NEG_INV_EPS * c0.x); o[1] = __expf(NEG_INV_EPS * c0.y);
    o[2] = __expf(NEG_INV_EPS * c0.z); o[3] = __expf(NEG_INV_EPS * c0.w);
    o[4] = __expf(NEG_INV_EPS * c1.x); o[5] = __expf(NEG_INV_EPS * c1.y);
    o[6] = __expf(NEG_INV_EPS * c1.z); o[7] = __expf(NEG_INV_EPS * c1.w);
    __half2 h[4];
    h[0] = __floats2half2_rn(o[0], o[1]);
    h[1] = __floats2half2_rn(o[2], o[3]);
    h[2] = __floats2half2_rn(o[4], o[5]);
    h[3] = __floats2half2_rn(o[6], o[7]);
    *raw = *reinterpret_cast<uint4*>(h);
  }
};

template <class KS>
__global__ void __launch_bounds__(512, 4) sink_iter(KS ks,
    const float* __restrict__ a, const float* __restrict__ bm,
    const float* __restrict__ s_cur, float* __restrict__ s_acc,
    float* __restrict__ s_zero, float* __restrict__ z_out) {
  __shared__ __align__(16) __half ksh[16][NN];
  __shared__ __align__(16) float wsh[NN];
  __shared__ float zsh[16];
  const int b = blockIdx.x >> 5;
  const int chunk = blockIdx.x & 31;
  const int tid = threadIdx.x;
  const int bbase = b * NN;

  {
    const float4 b4 = *reinterpret_cast<const float4*>(bm + bbase + tid * 4);
    const float4 s4 = *reinterpret_cast<const float4*>(s_cur + bbase + tid * 4);
    float4 w4;
    w4.x = b4.x * __builtin_amdgcn_rcpf(s4.x);
    w4.y = b4.y * __builtin_amdgcn_rcpf(s4.y);
    w4.z = b4.z * __builtin_amdgcn_rcpf(s4.z);
    w4.w = b4.w * __builtin_amdgcn_rcpf(s4.w);
    *reinterpret_cast<float4*>(&wsh[tid * 4]) = w4;
  }
  if (tid < 64) s_zero[bbase + chunk * 64 + tid] = 0.0f;
  __syncthreads();

  const int wave = tid >> 6;
  const int lane = tid & 63;

  float wreg[32];
#pragma unroll
  for (int k = 0; k < 4; ++k) {
    const float4* w4 = reinterpret_cast<const float4*>(&wsh[k * 512 + lane * 8]);
    const float4 wa = w4[0], wb = w4[1];
    wreg[k * 8 + 0] = wa.x; wreg[k * 8 + 1] = wa.y;
    wreg[k * 8 + 2] = wa.z; wreg[k * 8 + 3] = wa.w;
    wreg[k * 8 + 4] = wb.x; wreg[k * 8 + 5] = wb.y;
    wreg[k * 8 + 6] = wb.z; wreg[k * 8 + 7] = wb.w;
  }

  const int r0 = chunk * 64;
  const int mycol = tid * 4;
  float colacc[4] = {0.f, 0.f, 0.f, 0.f};

  for (int sc = 0; sc < 4; ++sc) {
    const int rowbase = r0 + sc * 16;
#pragma unroll
    for (int rr = 0; rr < 2; ++rr) {
      const int lrow = wave * 2 + rr;
      const int row = rowbase + lrow;
      const size_t kb = ((size_t)(b * MM + row)) * NN;
      float acc = 0.f;
#pragma unroll
      for (int k = 0; k < 4; ++k) {
        float kv[8];
        uint4 raw;
        ks.load8h(kb + k * 512 + lane * 8, kv, &raw);
        *reinterpret_cast<uint4*>(&ksh[lrow][k * 512 + lane * 8]) = raw;
#pragma unroll
        for (int m = 0; m < 8; ++m) acc += kv[m] * wreg[k * 8 + m];
      }
#pragma unroll
      for (int off = 32; off; off >>= 1) acc += __shfl_xor(acc, off, 64);
      if (lane == 0) {
        const float zv = a[b * MM + row] * __builtin_amdgcn_rcpf(acc);
        zsh[lrow] = zv;
        z_out[b * MM + row] = zv;
      }
    }
    __syncthreads();
#pragma unroll 4
    for (int r = 0; r < 16; ++r) {
      const float zi = zsh[r];
      uint2 rv = *reinterpret_cast<const uint2*>(&ksh[r][mycol]);
      const __half2* h = reinterpret_cast<const __half2*>(&rv);
      const float2 f01 = __half22float2(h[0]);
      const float2 f23 = __half22float2(h[1]);
      colacc[0] += f01.x * zi;
      colacc[1] += f01.y * zi;
      colacc[2] += f23.x * zi;
      colacc[3] += f23.y * zi;
    }
    __syncthreads();
  }

  float* s = s_acc + bbase + mycol;
#pragma unroll
  for (int m = 0; m < 4; ++m) atomicAdd(&s[m], colacc[m]);
}

// ---- Final: P = z_i * exp(-C/eps) * w_j (exact C), dist = sum(P*C). ----
// sw is either w directly (is_w=1, coop path) or s (is_w=0, legacy path).

__global__ void __launch_bounds__(256) final_pass(const float* __restrict__ C,
    const float* __restrict__ z, const float* __restrict__ bm,
    const float* __restrict__ sw, const int is_w, float* __restrict__ out) {
  __shared__ __align__(16) float wsh[NN];
  __shared__ float zsh[16];
  __shared__ float red[256];
  const int b = blockIdx.x >> 7;        // / 128
  const int rc = blockIdx.x & 127;
  const int tid = threadIdx.x;
  const int bbase = b * NN;

  for (int j = tid; j < NN; j += 256)
    wsh[j] = is_w ? sw[bbase + j]
                  : bm[bbase + j] * __builtin_amdgcn_rcpf(sw[bbase + j]);
  if (tid < 16) zsh[tid] = z[b * MM + rc * 16 + tid];
  __syncthreads();

  float* __restrict__ P = out + NB;
  const int col = tid * 8;
  const float4* w4 = reinterpret_cast<const float4*>(&wsh[col]);
  const float4 wa = w4[0], wb = w4[1];

  float accd = 0.0f;
#pragma unroll 4
  for (int rr = 0; rr < 16; ++rr) {
    const int row = rc * 16 + rr;
    const float zi = zsh[rr];
    const size_t base = ((size_t)(b * MM + row)) * NN + col;
    float4 c0 = *reinterpret_cast<const float4*>(C + base);
    float4 c1 = *reinterpret_cast<const float4*>(C + base + 4);
    float4 p0, p1;
    p0.x = zi * __expf(NEG_INV_EPS * c0.x) * wa.x;
    p0.y = zi * __expf(NEG_INV_EPS * c0.y) * wa.y;
    p0.z = zi * __expf(NEG_INV_EPS * c0.z) * wa.z;
    p0.w = zi * __expf(NEG_INV_EPS * c0.w) * wa.w;
    p1.x = zi * __expf(NEG_INV_EPS * c1.x) * wb.x;
    p1.y = zi * __expf(NEG_INV_EPS * c1.y) * wb.y;
    p1.z = zi * __expf(NEG_INV_EPS * c1.z) * wb.z;
    p1.w = zi * __expf(NEG_INV_EPS * c1.w) * wb.w;
    *reinterpret_cast<float4*>(P + base) = p0;
    *reinterpret_cast<float4*>(P + base + 4) = p1;
    accd += p0.x * c0.x + p0.y * c0.y + p0.z * c0.z + p0.w * c0.w +
            p1.x * c1.x + p1.y * c1.y + p1.z * c1.z + p1.w * c1.w;
  }

  red[tid] = accd;
  __syncthreads();
  if (tid < 128) red[tid] += red[tid + 128];
  __syncthreads();
  if (tid < 64) {
    float v = red[tid] + red[tid + 64];
#pragma unroll
    for (int off = 32; off; off >>= 1) v += __shfl_xor(v, off, 64);
    if (tid == 0) atomicAdd(&out[b], v);
  }
}

}  // namespace

extern "C" void kernel_launch(void* const* d_in, const int* in_sizes, int n_in,
                              void* d_out, int out_size, void* d_ws, size_t ws_size,
                              hipStream_t stream) {
  const float* C  = (const float*)d_in[0];
  const float* a  = (const float*)d_in[1];
  const float* bm = (const float*)d_in[2];
  float* out = (float*)d_out;
  char* ws = (char*)d_ws;

  const size_t VEC = (size_t)NB * MM * sizeof(float);          // 131072 B
  const size_t PART = (size_t)NB * 32 * NN * sizeof(float);    // 4 MB
  const size_t KBYTES = (size_t)NB * MM * NN * sizeof(__half); // 134 MB

  hipMemsetAsync(out, 0, NB * sizeof(float), stream);

  // ---- coop path: one cooperative kernel for all 100 iterations ----
  int maxb = 0;
  (void)hipOccupancyMaxActiveBlocksPerMultiprocessor(&maxb, sink_coop, 512, 0);
  const bool canCoop = (maxb >= 2) && (ws_size >= 2 * VEC + PART + KBYTES);

  if (canCoop) {
    float* z = (float*)(ws);
    float* wbuf = (float*)(ws + VEC);
    float* partial = (float*)(ws + 2 * VEC);
    __half* K = (__half*)(ws + 2 * VEC + PART);
    build_k<<<8192, 256, 0, stream>>>(C, K);
    void* args[6] = {(void*)&K, (void*)&a, (void*)&bm,
                     (void*)&z, (void*)&wbuf, (void*)&partial};
    hipLaunchCooperativeKernel((const void*)sink_coop, dim3(NB * 32), dim3(512),
                               args, 0, stream);
    final_pass<<<NB * 128, 256, 0, stream>>>(C, z, bm, wbuf, 1, out);
    return;
  }

  // ---- legacy paths ----
  float* z = (float*)(ws);
  float* s[3] = {(float*)(ws + VEC), (float*)(ws + 2 * VEC), (float*)(ws + 3 * VEC)};
  __half* K = (__half*)(ws + 4 * VEC);
  const bool useHalf = (ws_size >= 4 * VEC + KBYTES);

  hipMemcpyAsync(s[0], bm, (size_t)NB * NN * sizeof(float),
                 hipMemcpyDeviceToDevice, stream);
  hipMemsetAsync(s[1], 0, (size_t)NB * NN * sizeof(float), stream);

  if (useHalf) {
    build_k<<<8192, 256, 0, stream>>>(C, K);
    for (int t = 0; t < ITERS; ++t) {
      sink_iter_h<<<NB * 32, 512, 0, stream>>>(
          K, a, bm, s[t % 3], s[(t + 1) % 3], s[(t + 2) % 3], z);
    }
  } else {
    KFromC ks{C};
    for (int t = 0; t < ITERS; ++t) {
      sink_iter<KFromC><<<NB * 32, 512, 0, stream>>>(
          ks, a, bm, s[t % 3], s[(t + 1) % 3], s[(t + 2) % 3], z);
    }
  }

  final_pass<<<NB * 128, 256, 0, stream>>>(C, z, bm, s[ITERS % 3], 0, out);
}